// Round 4
// baseline (10158.245 us; speedup 1.0000x reference)
//
#include <hip/hip_runtime.h>
#include <hip/hip_bf16.h>

// LiquidRNN on MI355X — round 6 (round-5 resubmit; round-5 bench died to an
// infra container failure, same signature as round 1 which reran clean).
// u_t = [x_t; h_t] @ Mfull + c  (Mfull = Wb@Wh, exact reassociation),
// d = tanh(u), h += (d-h)/tau.
//
// Decomposition: WG(g,s) = batch-group g (16 batches) x H-slice s (64 cols).
// 32 WGs x 256 threads; each wave owns 16 output cols; weight slice
// (24 A-fragments = 96 VGPRs) register-resident for the whole kernel.
//
// Exchange protocol:
//   * Payload: SELF-VALIDATING tagged dwords {bf16 h | t<<16} via agent-scope
//     atomics (exact layout that passed round 4 — tags are the ground truth,
//     only same-address coherence needed, no cross-address ordering).
//   * Hint: per-WG flag[g][s] = t+1, stored (NOT fetch_add — no LLC RMW
//     serialization) after payload-store drain + __syncthreads. Consumer
//     spins on 8 flags (4 u64 loads + min-tree per retry — cheap), then
//     loads payload and tag-checks ONCE; rare mismatch falls into a
//     reload-recheck loop. Flag mis-ordering is harmless: tags catch it.
//   * Overlap: after spin, payload loads + next-step x prefetch issue first,
//     then the 8 x-part MFMAs run before the tag check (hides load latency).
//     x->bf16 via v_cvt_pk_bf16_f32; tag-strip unpack via v_perm_b32.
// Liveness/anti-overwrite structural (all-to-all per group): a WG stores
// payload t+2 only after all WGs flagged t+1, and flag t+1 is preceded by
// vmcnt(0) which drains that WG's payload-t loads. hbuf+flags zeroed in
// k_prep => replay-safe (tags 1..1024 never match 0 or 0xAAAA poison).

#define S_   1024
#define D_   256
#define H_   512
#define KT_  768   // D_+H_
#define NKC_ 24    // KT_/32

typedef __attribute__((ext_vector_type(4))) float f32x4;
typedef __attribute__((ext_vector_type(8))) short bf16x8;
typedef unsigned long long u64;
typedef unsigned int u32;

static __device__ __forceinline__ unsigned short f2bf(float f) {
    unsigned int x = __float_as_uint(f);
    return (unsigned short)((x + 0x7fffu + ((x >> 16) & 1u)) >> 16);
}

// ---------------- k_prep: Mfrag (fragment order), c, itau, zero hbuf+flags ----
__global__ void k_prep(const float* __restrict__ Wb, const float* __restrict__ bb,
                       const float* __restrict__ Wh, const float* __restrict__ bh,
                       const float* __restrict__ tau,
                       unsigned short* __restrict__ Mfrag, float* __restrict__ c,
                       float* __restrict__ itau, u32* __restrict__ hz) {
    int i = blockIdx.x * 256 + threadIdx.x;
    if (i < KT_ * H_) {
        int r = i >> 9, n = i & 511;
        float acc = 0.f;
        for (int u = 0; u < 512; ++u)
            acc += Wb[r * 512 + u] * Wh[u * 512 + n];
        int kc   = r >> 5;
        int j    = r & 7;
        int lane = (((r >> 3) & 3) << 4) | (n & 15);
        int nt   = n >> 4;
        Mfrag[((nt * NKC_ + kc) * 64 + lane) * 8 + j] = f2bf(acc);
    } else if (i < KT_ * H_ + 512) {
        int n = i - KT_ * H_;
        float acc = bh[n];
        for (int u = 0; u < 512; ++u)
            acc += bb[u] * Wh[u * 512 + n];
        c[n] = acc;
    } else if (i < KT_ * H_ + 1024) {
        itau[i - KT_ * H_ - 512] = 1.0f / tau[i - KT_ * H_ - 512];
    } else {
        int z = i - KT_ * H_ - 1024;
        if (z < 65536 + 64) hz[z] = 0u;   // hbuf tags + flags: 0 never matches
    }
}

// ---------------- k_rnn2 --------------------------------------------------------
// hbuf dword layout within a (g,parity) slot of 8192 dwords (4096 u64):
//   dword[(oct*16 + batch)*8 + (hcol&7)], oct = hcol>>3, batch = b&15,
//   value = bf16(h[batch][hcol]) | (tag<<16).
__global__ __launch_bounds__(256, 1)
void k_rnn2(const float* __restrict__ x, const unsigned short* __restrict__ Mfrag,
            const float* __restrict__ c, const float* __restrict__ itau,
            u64* __restrict__ hb, u32* __restrict__ fl, float* __restrict__ out) {
    const int g    = blockIdx.x >> 3;      // batch group 0..3
    const int s    = blockIdx.x & 7;       // h-slice 0..7
    const int tid  = threadIdx.x;
    const int w    = tid >> 6;             // wave 0..3
    const int lane = tid & 63;
    const int quad = lane >> 4;
    const int m16  = lane & 15;
    const int nt   = s * 4 + w;            // global 16-col tile 0..31
    const int C0   = nt * 16 + quad * 4;   // this lane's 4 output cols
    const int b    = g * 16 + m16;         // this lane's batch (B-operand n)

    // ---- weights: 24 A-fragments, register-resident ----
    const bf16x8* Mf = reinterpret_cast<const bf16x8*>(Mfrag);
    bf16x8 wreg[NKC_];
#pragma unroll
    for (int kc = 0; kc < NKC_; ++kc)
        wreg[kc] = Mf[(nt * NKC_ + kc) * 64 + lane];

    const f32x4 cs = *reinterpret_cast<const f32x4*>(c + C0);
    const f32x4 ts = *reinterpret_cast<const f32x4*>(itau + C0);

    // ---- exchange lane constants (u64 units within a 4096-u64 slot) ----
    const int jsel = quad & 1;
    const int st_u = ((C0 >> 3) * 16 + m16) * 4 + jsel * 2;  // producer: 2 u64
    const int ld_u = lane * 4;                               // consumer: +kc*256
    u64* flq = reinterpret_cast<u64*>(fl) + g * 8;           // 8 flags = 4 u64

    // ---- prologue: load + convert x(0) ----
    f32x4 xr[16];
    {
        const float* xq = x + (size_t)b * (S_ * D_) + quad * 8;
#pragma unroll
        for (int kc = 0; kc < 8; ++kc) {
            xr[2 * kc]     = *reinterpret_cast<const f32x4*>(xq + kc * 32);
            xr[2 * kc + 1] = *reinterpret_cast<const f32x4*>(xq + kc * 32 + 4);
        }
    }
    bf16x8 xv[8];
#pragma unroll
    for (int kc = 0; kc < 8; ++kc) {
        union { u32 u[4]; bf16x8 v; } t_;
#pragma unroll
        for (int j = 0; j < 4; ++j) {
            float lo = (j < 2) ? xr[2 * kc][2 * j]     : xr[2 * kc + 1][2 * j - 4];
            float hi = (j < 2) ? xr[2 * kc][2 * j + 1] : xr[2 * kc + 1][2 * j - 3];
            asm("v_cvt_pk_bf16_f32 %0, %1, %2" : "=v"(t_.u[j]) : "v"(lo), "v"(hi));
        }
        xv[kc] = t_.v;
    }

    f32x4 h_old = {0.f, 0.f, 0.f, 0.f};

    for (int t = 0; t < S_; ++t) {
        u64 hl[16][4];
        u64* hbl = hb + (size_t)(g * 2 + (t & 1)) * 4096;

        if (t > 0) {
            // ---- cheap spin: all 8 WG flags >= t ----
            for (;;) {
                u64 f0 = __hip_atomic_load(flq + 0, __ATOMIC_RELAXED, __HIP_MEMORY_SCOPE_AGENT);
                u64 f1 = __hip_atomic_load(flq + 1, __ATOMIC_RELAXED, __HIP_MEMORY_SCOPE_AGENT);
                u64 f2 = __hip_atomic_load(flq + 2, __ATOMIC_RELAXED, __HIP_MEMORY_SCOPE_AGENT);
                u64 f3 = __hip_atomic_load(flq + 3, __ATOMIC_RELAXED, __HIP_MEMORY_SCOPE_AGENT);
                u32 m = (u32)f0;
                m = min(m, (u32)(f0 >> 32));
                m = min(m, (u32)f1); m = min(m, (u32)(f1 >> 32));
                m = min(m, (u32)f2); m = min(m, (u32)(f2 >> 32));
                m = min(m, (u32)f3); m = min(m, (u32)(f3 >> 32));
                if (m >= (u32)t) break;
            }
            // ---- issue payload loads (latency hidden under x-MFMAs below) ----
#pragma unroll
            for (int kc = 0; kc < 16; ++kc) {
#pragma unroll
                for (int q = 0; q < 4; ++q)
                    hl[kc][q] = __hip_atomic_load(hbl + kc * 256 + ld_u + q,
                                                  __ATOMIC_RELAXED, __HIP_MEMORY_SCOPE_AGENT);
            }
        }

        // ---- x prefetch for t+1 (plain loads, consumed at iteration end) ----
        {
            int tn = (t + 1) & (S_ - 1);
            const float* xq = x + ((size_t)b * S_ + tn) * D_ + quad * 8;
#pragma unroll
            for (int kc = 0; kc < 8; ++kc) {
                xr[2 * kc]     = *reinterpret_cast<const f32x4*>(xq + kc * 32);
                xr[2 * kc + 1] = *reinterpret_cast<const f32x4*>(xq + kc * 32 + 4);
            }
        }

        // ---- x-part MFMAs (run while payload loads are in flight) ----
        f32x4 aA = {0.f, 0.f, 0.f, 0.f}, aB = aA, aC = aA, aD = aA;
#pragma unroll
        for (int kc = 0; kc < 8; ++kc) {
            if (kc & 1) aB = __builtin_amdgcn_mfma_f32_16x16x32_bf16(wreg[kc], xv[kc], aB, 0, 0, 0);
            else        aA = __builtin_amdgcn_mfma_f32_16x16x32_bf16(wreg[kc], xv[kc], aA, 0, 0, 0);
        }

        if (t > 0) {
            // ---- tag check (once; rare retry loop on fabric race) ----
            const u64 TT = ((u64)(u32)t << 48) | ((u64)(u32)t << 16);
            for (;;) {
                u64 bad = 0;
#pragma unroll
                for (int kc = 0; kc < 16; ++kc) {
#pragma unroll
                    for (int q = 0; q < 4; ++q)
                        bad |= (hl[kc][q] ^ TT);
                }
                bad &= 0xFFFF0000FFFF0000ull;
                if (!__any(bad != 0ull)) break;
#pragma unroll
                for (int kc = 0; kc < 16; ++kc) {
#pragma unroll
                    for (int q = 0; q < 4; ++q)
                        hl[kc][q] = __hip_atomic_load(hbl + kc * 256 + ld_u + q,
                                                      __ATOMIC_RELAXED, __HIP_MEMORY_SCOPE_AGENT);
                }
            }
            // ---- unpack (v_perm strips tags) + h-part MFMAs, 4 acc chains ----
#pragma unroll
            for (int kc = 0; kc < 16; ++kc) {
                union { u32 u[4]; bf16x8 v; } hv;
#pragma unroll
                for (int q = 0; q < 4; ++q)
                    hv.u[q] = __builtin_amdgcn_perm((u32)(hl[kc][q] >> 32),
                                                    (u32)hl[kc][q], 0x05040100u);
                switch (kc & 3) {
                    case 0: aA = __builtin_amdgcn_mfma_f32_16x16x32_bf16(wreg[8 + kc], hv.v, aA, 0, 0, 0); break;
                    case 1: aB = __builtin_amdgcn_mfma_f32_16x16x32_bf16(wreg[8 + kc], hv.v, aB, 0, 0, 0); break;
                    case 2: aC = __builtin_amdgcn_mfma_f32_16x16x32_bf16(wreg[8 + kc], hv.v, aC, 0, 0, 0); break;
                    default: aD = __builtin_amdgcn_mfma_f32_16x16x32_bf16(wreg[8 + kc], hv.v, aD, 0, 0, 0); break;
                }
            }
        }

        // ---- epilogue: u -> tanh -> liquid Euler update, tagged dwords ----
        f32x4 acc = (aA + aB) + (aC + aD);
        f32x4 hn;
        u32 dv[4];
        const u32 Tn = (u32)(t + 1) << 16;
#pragma unroll
        for (int r = 0; r < 4; ++r) {
            float u = acc[r] + cs[r];
            float e = __expf(2.f * u);
            float d = 1.f - 2.f / (e + 1.f);          // tanh(u), robust at +-inf
            hn[r] = h_old[r] + (d - h_old[r]) * ts[r];
            dv[r] = (u32)f2bf(hn[r]) | Tn;
        }
        h_old = hn;

        // ---- h_{t+1} payload (parity (t+1)&1) ----
        u64 p0 = (u64)dv[0] | ((u64)dv[1] << 32);
        u64 p1 = (u64)dv[2] | ((u64)dv[3] << 32);
        u64* hbs = hb + (size_t)(g * 2 + ((t + 1) & 1)) * 4096;
        __hip_atomic_store(hbs + st_u,     p0, __ATOMIC_RELAXED, __HIP_MEMORY_SCOPE_AGENT);
        __hip_atomic_store(hbs + st_u + 1, p1, __ATOMIC_RELAXED, __HIP_MEMORY_SCOPE_AGENT);

        // drain payload stores AND this step's payload loads, then flag store.
        // (Load-drain before flag is what makes overwrite of the parity slot
        // provably safe — see header.)
        asm volatile("s_waitcnt vmcnt(0)" ::: "memory");
        __syncthreads();
        if (tid == 0)
            __hip_atomic_store(fl + g * 16 + s, (u32)(t + 1),
                               __ATOMIC_RELAXED, __HIP_MEMORY_SCOPE_AGENT);

        // out store — off the protocol critical path
        *reinterpret_cast<f32x4*>(out + ((size_t)b * S_ + t) * H_ + C0) = hn;

        // ---- convert x(t+1) (prefetched above; landed during hMFMA/epilogue) --
#pragma unroll
        for (int kc = 0; kc < 8; ++kc) {
            union { u32 u[4]; bf16x8 v; } t_;
#pragma unroll
            for (int j = 0; j < 4; ++j) {
                float lo = (j < 2) ? xr[2 * kc][2 * j]     : xr[2 * kc + 1][2 * j - 4];
                float hi = (j < 2) ? xr[2 * kc][2 * j + 1] : xr[2 * kc + 1][2 * j - 3];
                asm("v_cvt_pk_bf16_f32 %0, %1, %2" : "=v"(t_.u[j]) : "v"(lo), "v"(hi));
            }
            xv[kc] = t_.v;
        }
    }
}

// ---------------- launch --------------------------------------------------------
extern "C" void kernel_launch(void* const* d_in, const int* in_sizes, int n_in,
                              void* d_out, int out_size, void* d_ws, size_t ws_size,
                              hipStream_t stream) {
    const float* x   = (const float*)d_in[0];  // [64,1024,256]
    const float* Wb  = (const float*)d_in[1];
    const float* bb  = (const float*)d_in[2];
    const float* Wh  = (const float*)d_in[3];
    const float* bh  = (const float*)d_in[4];
    const float* tau = (const float*)d_in[5];
    float* out = (float*)d_out;                // [64,1024,512] fp32

    char* ws = (char*)d_ws;
    unsigned short* Mfrag = (unsigned short*)ws;             //   786,432 B
    float*          c     = (float*)(ws + 786432);           //     2,048 B
    float*          it    = (float*)(ws + 788480);           //     2,048 B
    u64*            hbuf  = (u64*)(ws + 790528);             //   262,144 B
    u32*            flags = (u32*)(ws + 1052672);            //       256 B
    // total ws use: 1,052,928 B

    hipLaunchKernelGGL(k_prep, dim3(1797), dim3(256), 0, stream,
                       Wb, bb, Wh, bh, tau, Mfrag, c, it, (u32*)hbuf);
    hipLaunchKernelGGL(k_rnn2, dim3(32), dim3(256), 0, stream,
                       x, Mfrag, c, it, hbuf, flags, out);
}